// Round 4
// baseline (182.273 us; speedup 1.0000x reference)
//
#include <hip/hip_runtime.h>
#include <hip/hip_bf16.h>

// GCN. CSR via 2-pass LDS bucket sort (R1: global-atomic count = 86us; LDS build ~15us).
// R2: agg_x fused into w1w2. R3: sW2 dropped from LDS (6 blocks/CU) -> 180.8us.
// R4 model: harness's 268MB poison fill wipes LLC each iter -> inter-kernel tables are
// served from DRAM, replicated once per XCD L2 (FETCH = table x 8 + cross-XCD csr).
// Levers: (a) xb rows 32B->24B (table 4->3MB: less DRAM fill AND fits 4MB L2 ->
// second touches hit); (b) w1w2 8 blocks/CU (sW1->global, sA pitch 13, LDS 19.5KB)
// + 8-edges-in-flight gather. Numerics bit-identical to R3.
// Layer 2: single 8 MB fp8 table (R17: splitting doubles per-edge line requests).

#define N_NODES 131072
#define N_EDGES 2097152
#define N_GRAPHS 2048
#define IN_CH 12
#define HID 64
#define OUT_CH 4
#define NBUCK 512          // buckets of 256 dst nodes
#define CHUNK 8192         // edges per bucket_kernel block
#define STRIDE 4608        // staging capacity per bucket (mean 4096, sd 64)
#define CSR_STRIDE 5120    // csr capacity per bucket (padded mean ~4500)
#define CAP 5120           // build_kernel LDS image capacity (20.5 KB, int)

typedef float f32x2 __attribute__((ext_vector_type(2)));

__device__ __forceinline__ unsigned short f2bf(float f) {
    unsigned u = __float_as_uint(f);
    return (unsigned short)((u + 0x7fffu + ((u >> 16) & 1u)) >> 16);  // RNE
}
__device__ __forceinline__ unsigned pack2bf(float lo, float hi) {
    return (unsigned)f2bf(lo) | ((unsigned)f2bf(hi) << 16);
}
__device__ __forceinline__ float bflo(unsigned v) { return __uint_as_float(v << 16); }
__device__ __forceinline__ float bfhi(unsigned v) { return __uint_as_float(v & 0xFFFF0000u); }

// ---- pass A: LDS bucket sort of edges by dst>>8 into strided staging ----
__global__ __launch_bounds__(1024, 4)
void bucket_kernel(const int* __restrict__ src, const int* __restrict__ dst,
                   int* __restrict__ bucket_count, int* __restrict__ staged) {
    __shared__ int hist[NBUCK];
    __shared__ int lscan[NBUCK];
    __shared__ int gbase[NBUCK];
    __shared__ int cursor[NBUCK];
    __shared__ int sorted[CHUNK];  // 32 KB
    int tid = threadIdx.x;
    int base = blockIdx.x * CHUNK;
    if (tid < NBUCK) { hist[tid] = 0; cursor[tid] = 0; }
    __syncthreads();
    int d8[8], s8[8];
#pragma unroll
    for (int k = 0; k < 8; k++) {
        int i = base + k * 1024 + tid;
        d8[k] = dst[i];
        s8[k] = src[i];
        atomicAdd(&hist[d8[k] >> 8], 1);
    }
    __syncthreads();
    if (tid < NBUCK) lscan[tid] = hist[tid];
    __syncthreads();
    for (int off = 1; off < NBUCK; off <<= 1) {
        int u = (tid < NBUCK && tid >= off) ? lscan[tid - off] : 0;
        __syncthreads();
        if (tid < NBUCK) lscan[tid] += u;
        __syncthreads();
    }
    if (tid < NBUCK) gbase[tid] = atomicAdd(&bucket_count[tid], hist[tid]);
    __syncthreads();
#pragma unroll
    for (int k = 0; k < 8; k++) {
        int b = d8[k] >> 8;
        int start = lscan[b] - hist[b];
        int p = start + atomicAdd(&cursor[b], 1);
        sorted[p] = ((d8[k] & 255) << 17) | s8[k];
    }
    __syncthreads();
    int wid = tid >> 6, lane = tid & 63;
    int g16 = lane >> 4, k16 = lane & 15;
    for (int b0 = wid * 4; b0 < NBUCK; b0 += 64) {
        int b = b0 + g16;
        int cb = hist[b];
        int lbase = lscan[b] - cb;
        int gb = b * STRIDE + gbase[b];
        for (int k = k16; k < cb; k += 16) staged[gb + k] = sorted[lbase + k];
    }
}

// ---- per-bucket: count + scan + place in one kernel; + prescaled x cast ----
__global__ void build_kernel(const int* __restrict__ bucket_count, const int* __restrict__ staged,
                             int2* __restrict__ rowbounds, float* __restrict__ dinv,
                             int* __restrict__ csr, const float* __restrict__ x,
                             unsigned short* __restrict__ xb) {
    __shared__ int sl[STRIDE];     // 18.4 KB bucket slice
    __shared__ int image[CAP];     // 20.5 KB csr image (src<<6)
    __shared__ int cnt[256];
    __shared__ int scn[256];
    __shared__ int loff[256];
    __shared__ int cursor[256];
    __shared__ int totalS;
    int b = blockIdx.x;
    int tid = threadIdx.x;
    int count = bucket_count[b];
    const int* st = staged + b * STRIDE;
    cnt[tid] = 0;
    cursor[tid] = 0;
    for (int i = tid; i < count; i += 256) sl[i] = st[i];
    __syncthreads();
    for (int i = tid; i < count; i += 256) atomicAdd(&cnt[(sl[i] >> 17) & 255], 1);
    __syncthreads();
    int deg = cnt[tid];
    int degp = (deg + 3) & ~3;  // pad to x4
    scn[tid] = degp;
    __syncthreads();
    for (int off = 1; off < 256; off <<= 1) {
        int u = (tid >= off) ? scn[tid - off] : 0;
        __syncthreads();
        scn[tid] += u;
        __syncthreads();
    }
    int lo = scn[tid] - degp;
    loff[tid] = lo;
    int nbase = (b << 8) + tid;
    int gb = b * CSR_STRIDE;
    rowbounds[nbase] = make_int2(gb + lo, gb + lo + degp);
    float dv = rsqrtf((float)deg + 1.0f);
    dinv[nbase] = dv;
    if (tid == 255) totalS = lo + degp;
    {   // prescaled x cast: 12 bf16 ch = 24-B rows (3 MB table, L2-resident)
        const float* xp = x + nbase * IN_CH;
        unsigned o[6];
#pragma unroll
        for (int k = 0; k < 6; k++) o[k] = pack2bf(dv * xp[2 * k], dv * xp[2 * k + 1]);
        uint2* dstp = (uint2*)(xb + nbase * 12);
        dstp[0] = make_uint2(o[0], o[1]);
        dstp[1] = make_uint2(o[2], o[3]);
        dstp[2] = make_uint2(o[4], o[5]);
    }
    if (b == 0 && tid < 3)  // zero row N_NODES of xb (pad target)
        ((uint2*)(xb + (size_t)N_NODES * 12))[tid] = make_uint2(0, 0);
    __syncthreads();
    for (int i = tid; i < count; i += 256) {
        int rec = sl[i];
        int s = rec & 0x1FFFF;
        int dq = (rec >> 17) & 255;
        int p = loff[dq] + atomicAdd(&cursor[dq], 1);
        int val = s << 6;  // byte off into 64B fp8 row | >>4 then x3: short off in xb
        if (p < CAP) image[p] = val;
        else csr[gb + p] = val;
    }
    __syncthreads();
    int padval = N_NODES << 6;  // zero row
    for (int p = loff[tid] + deg; p < loff[tid] + degp; p++) {
        if (p < CAP) image[p] = padval;
        else csr[gb + p] = padval;
    }
    __syncthreads();
    int lim = totalS < CAP ? totalS : CAP;
    int* dstp = csr + gb;
    for (int i = tid; i < lim; i += 256) dstp[i] = image[i];
}

// ---- layer-1 bf16 gather helper: 6 ch (uint3) accumulate ----
__device__ __forceinline__ void acc3(f32x2* a, uint3 u) {
    a[0] += (f32x2){bflo(u.x), bfhi(u.x)};
    a[1] += (f32x2){bflo(u.y), bfhi(u.y)};
    a[2] += (f32x2){bflo(u.z), bfhi(u.z)};
}

// ---- fused layer-1 gather + w1 + w2, register-tiled: 64 nodes/block ----
// R4: LDS 19.5KB -> 8 blocks/CU; W1,W2 from global/L1; 8-edge-in-flight gather.
__global__ __launch_bounds__(256, 8)
void w1w2_kernel(const int2* __restrict__ rowbounds, const int* __restrict__ csr,
                 const float* __restrict__ dinv, const unsigned short* __restrict__ xb,
                 const float* __restrict__ W1, const float* __restrict__ b1,
                 const float* __restrict__ W2, unsigned int* __restrict__ hout) {
    __shared__ float sA[64 * 13];          // 3.3 KB (pitch 13: 12 ch + 1 pad)
    __shared__ float sh1t[HID * 65];       // 16.25 KB: h1^T [ch][node], pitch 65
    int tid = threadIdx.x;
    int node0 = blockIdx.x * 64;
    {   // gather phase: 4 thr/node = 2 edge-halves x 2 ch-halves (6 ch each)
        int nl = tid >> 2;
        int node = node0 + nl;
        int p = tid & 1, soff = 6 * p;  // shorts: p0 ch0-5, p1 ch6-11
        int2 rb = rowbounds[node];
        float dn = dinv[node];          // hoisted: issue early
        uint3 su = {0, 0, 0};
        if (!(tid & 2)) su = *(const uint3*)(xb + node * 12 + soff);  // hoisted
        int len = rb.y - rb.x;
        int hlen = (len >> 3) << 2;     // first half, mult of 4
        int beg = (tid & 2) ? rb.x + hlen : rb.x;
        int end = (tid & 2) ? rb.y : rb.x + hlen;
        f32x2 a0[3] = {{0, 0}, {0, 0}, {0, 0}};
        f32x2 a1[3] = {{0, 0}, {0, 0}, {0, 0}};
        f32x2 a2[3] = {{0, 0}, {0, 0}, {0, 0}};
        f32x2 a3[3] = {{0, 0}, {0, 0}, {0, 0}};
        int j = beg;
        for (; j + 8 <= end; j += 8) {  // 8 edges in flight
            int4 ea = *(const int4*)(csr + j);
            int4 eb = *(const int4*)(csr + j + 4);
            uint3 u0 = *(const uint3*)(xb + 3 * (ea.x >> 4) + soff);
            uint3 u1 = *(const uint3*)(xb + 3 * (ea.y >> 4) + soff);
            uint3 u2 = *(const uint3*)(xb + 3 * (ea.z >> 4) + soff);
            uint3 u3 = *(const uint3*)(xb + 3 * (ea.w >> 4) + soff);
            uint3 u4 = *(const uint3*)(xb + 3 * (eb.x >> 4) + soff);
            uint3 u5 = *(const uint3*)(xb + 3 * (eb.y >> 4) + soff);
            uint3 u6 = *(const uint3*)(xb + 3 * (eb.z >> 4) + soff);
            uint3 u7 = *(const uint3*)(xb + 3 * (eb.w >> 4) + soff);
            acc3(a0, u0); acc3(a1, u1); acc3(a2, u2); acc3(a3, u3);
            acc3(a0, u4); acc3(a1, u5); acc3(a2, u6); acc3(a3, u7);
        }
        if (j < end) {  // exactly 4 padded edges remain
            int4 ea = *(const int4*)(csr + j);
            uint3 u0 = *(const uint3*)(xb + 3 * (ea.x >> 4) + soff);
            uint3 u1 = *(const uint3*)(xb + 3 * (ea.y >> 4) + soff);
            uint3 u2 = *(const uint3*)(xb + 3 * (ea.z >> 4) + soff);
            uint3 u3 = *(const uint3*)(xb + 3 * (ea.w >> 4) + soff);
            acc3(a0, u0); acc3(a1, u1); acc3(a2, u2); acc3(a3, u3);
        }
        f32x2 s0 = (a0[0] + a1[0]) + (a2[0] + a3[0]);
        f32x2 s1 = (a0[1] + a1[1]) + (a2[1] + a3[1]);
        f32x2 s2 = (a0[2] + a1[2]) + (a2[2] + a3[2]);
        s0[0] += __shfl_xor(s0[0], 2); s0[1] += __shfl_xor(s0[1], 2);
        s1[0] += __shfl_xor(s1[0], 2); s1[1] += __shfl_xor(s1[1], 2);
        s2[0] += __shfl_xor(s2[0], 2); s2[1] += __shfl_xor(s2[1], 2);
        if (!(tid & 2)) {
            s0 += (f32x2){bflo(su.x), bfhi(su.x)};
            s1 += (f32x2){bflo(su.y), bfhi(su.y)};
            s2 += (f32x2){bflo(su.z), bfhi(su.z)};
            float* dp = &sA[nl * 13 + soff];
            dp[0] = dn * s0[0]; dp[1] = dn * s0[1];
            dp[2] = dn * s1[0]; dp[3] = dn * s1[1];
            dp[4] = dn * s2[0]; dp[5] = dn * s2[1];
        }
    }
    __syncthreads();
    // phase 1 (W1): wave w computes 16-node x 64-ch tile; lane = channel.
    // W1 column hoisted to 12 registers (global/L1, coalesced 256B per load).
    int w = tid >> 6, c = tid & 63;
    float bc = b1[c];
    float wk[IN_CH];
#pragma unroll
    for (int k = 0; k < IN_CH; k++) wk[k] = W1[k * HID + c];
#pragma unroll
    for (int it = 0; it < 4; it++) {
        int n0 = w * 16 + it * 4;
        float a0 = bc, a1 = bc, a2 = bc, a3 = bc;
#pragma unroll
        for (int k = 0; k < IN_CH; k++) {
            float wv = wk[k];
            a0 += sA[(n0 + 0) * 13 + k] * wv;  // sA reads broadcast per wave
            a1 += sA[(n0 + 1) * 13 + k] * wv;
            a2 += sA[(n0 + 2) * 13 + k] * wv;
            a3 += sA[(n0 + 3) * 13 + k] * wv;
        }
        float4 o = make_float4(fmaxf(a0, 0.0f), fmaxf(a1, 0.0f),
                               fmaxf(a2, 0.0f), fmaxf(a3, 0.0f));
        *(float4*)&sh1t[c * 65 + n0] = o;  // transposed: [ch][node]
    }
    __syncthreads();
    // phase 2 (W2): thread = 4 nodes x 4 ch; W2 from global (L1-resident 16KB)
    int nq = tid >> 4, c4 = (tid & 15) * 4;
    float4 a0 = {0, 0, 0, 0}, a1 = {0, 0, 0, 0}, a2 = {0, 0, 0, 0}, a3 = {0, 0, 0, 0};
#pragma unroll 4
    for (int k = 0; k < HID; k++) {
        float4 wv = *(const float4*)&W2[k * HID + c4];
        float4 hv = *(const float4*)&sh1t[k * 65 + nq * 4];  // 4 nodes' h1[k]
        a0.x += hv.x * wv.x; a0.y += hv.x * wv.y; a0.z += hv.x * wv.z; a0.w += hv.x * wv.w;
        a1.x += hv.y * wv.x; a1.y += hv.y * wv.y; a1.z += hv.y * wv.z; a1.w += hv.y * wv.w;
        a2.x += hv.z * wv.x; a2.y += hv.z * wv.y; a2.z += hv.z * wv.z; a2.w += hv.z * wv.w;
        a3.x += hv.w * wv.x; a3.y += hv.w * wv.y; a3.z += hv.w * wv.z; a3.w += hv.w * wv.w;
    }
    int nb = node0 + nq * 4;
    float dv0 = dinv[nb + 0], dv1 = dinv[nb + 1], dv2 = dinv[nb + 2], dv3 = dinv[nb + 3];
    unsigned int p0 = (unsigned int)__builtin_amdgcn_cvt_pk_fp8_f32(dv0 * a0.x, dv0 * a0.y, 0, false);
    p0 = (unsigned int)__builtin_amdgcn_cvt_pk_fp8_f32(dv0 * a0.z, dv0 * a0.w, (int)p0, true);
    unsigned int p1 = (unsigned int)__builtin_amdgcn_cvt_pk_fp8_f32(dv1 * a1.x, dv1 * a1.y, 0, false);
    p1 = (unsigned int)__builtin_amdgcn_cvt_pk_fp8_f32(dv1 * a1.z, dv1 * a1.w, (int)p1, true);
    unsigned int p2 = (unsigned int)__builtin_amdgcn_cvt_pk_fp8_f32(dv2 * a2.x, dv2 * a2.y, 0, false);
    p2 = (unsigned int)__builtin_amdgcn_cvt_pk_fp8_f32(dv2 * a2.z, dv2 * a2.w, (int)p2, true);
    unsigned int p3 = (unsigned int)__builtin_amdgcn_cvt_pk_fp8_f32(dv3 * a3.x, dv3 * a3.y, 0, false);
    p3 = (unsigned int)__builtin_amdgcn_cvt_pk_fp8_f32(dv3 * a3.z, dv3 * a3.w, (int)p3, true);
    int cl = c4 >> 2;
    hout[(nb + 0) * 16 + cl] = p0;   // per-instruction: 64B runs, fully coalesced
    hout[(nb + 1) * 16 + cl] = p1;
    hout[(nb + 2) * 16 + cl] = p2;
    hout[(nb + 3) * 16 + cl] = p3;
    if (blockIdx.x == 0 && tid < 16)  // zero row N_NODES (pad target)
        hout[(size_t)N_NODES * 16 + tid] = 0;
}

// ---- layer-2 fp8 gather body: 4 thr/node, uint4 (16 ch); 8 edges in flight ----
__device__ __forceinline__ void add_fp8q(f32x2* a, uint4 u) {
    a[0] += __builtin_amdgcn_cvt_pk_f32_fp8((int)u.x, false);
    a[1] += __builtin_amdgcn_cvt_pk_f32_fp8((int)u.x, true);
    a[2] += __builtin_amdgcn_cvt_pk_f32_fp8((int)u.y, false);
    a[3] += __builtin_amdgcn_cvt_pk_f32_fp8((int)u.y, true);
    a[4] += __builtin_amdgcn_cvt_pk_f32_fp8((int)u.z, false);
    a[5] += __builtin_amdgcn_cvt_pk_f32_fp8((int)u.z, true);
    a[6] += __builtin_amdgcn_cvt_pk_f32_fp8((int)u.w, false);
    a[7] += __builtin_amdgcn_cvt_pk_f32_fp8((int)u.w, true);
}

__device__ __forceinline__ void agg_body16(int beg, int end, const int* __restrict__ csr,
                                           const unsigned char* __restrict__ h,
                                           int qoff, float* r) {
    f32x2 a0[8] = {{0, 0}, {0, 0}, {0, 0}, {0, 0}, {0, 0}, {0, 0}, {0, 0}, {0, 0}};
    f32x2 a1[8] = {{0, 0}, {0, 0}, {0, 0}, {0, 0}, {0, 0}, {0, 0}, {0, 0}, {0, 0}};
    int j = beg;
    for (; j + 8 <= end; j += 8) {  // 8 edges in flight
        int4 ea = *(const int4*)(csr + j);
        int4 eb = *(const int4*)(csr + j + 4);
        uint4 u0 = *(const uint4*)(h + ea.x + qoff);
        uint4 u1 = *(const uint4*)(h + ea.y + qoff);
        uint4 u2 = *(const uint4*)(h + ea.z + qoff);
        uint4 u3 = *(const uint4*)(h + ea.w + qoff);
        uint4 u4 = *(const uint4*)(h + eb.x + qoff);
        uint4 u5 = *(const uint4*)(h + eb.y + qoff);
        uint4 u6 = *(const uint4*)(h + eb.z + qoff);
        uint4 u7 = *(const uint4*)(h + eb.w + qoff);
        add_fp8q(a0, u0); add_fp8q(a1, u1); add_fp8q(a0, u2); add_fp8q(a1, u3);
        add_fp8q(a0, u4); add_fp8q(a1, u5); add_fp8q(a0, u6); add_fp8q(a1, u7);
    }
    if (j < end) {  // exactly 4 padded edges remain
        int4 ea = *(const int4*)(csr + j);
        uint4 u0 = *(const uint4*)(h + ea.x + qoff);
        uint4 u1 = *(const uint4*)(h + ea.y + qoff);
        uint4 u2 = *(const uint4*)(h + ea.z + qoff);
        uint4 u3 = *(const uint4*)(h + ea.w + qoff);
        add_fp8q(a0, u0); add_fp8q(a1, u1); add_fp8q(a0, u2); add_fp8q(a1, u3);
    }
#pragma unroll
    for (int k = 0; k < 8; k++) {
        f32x2 s = a0[k] + a1[k];
        r[2 * k] = s[0];
        r[2 * k + 1] = s[1];
    }
}

// ---- layer-2 gather-aggregate + relu + fused mean-pool (run-length flush) ----
__global__ void agg_pool_kernel(const int2* __restrict__ rowbounds, const int* __restrict__ csr,
                                const float* __restrict__ dinv,
                                const unsigned char* __restrict__ h,
                                const float* __restrict__ b, const int* __restrict__ batch,
                                float* __restrict__ pool, float* __restrict__ gcnt) {
    __shared__ float red[64][HID + 4];  // 17 KB, padded pitch kills bank conflicts
    __shared__ int gids[64];
    int tid = threadIdx.x;
    int w = tid >> 6, lane = tid & 63, sub = lane >> 2, q = lane & 3;
    int qoff = 16 * q;  // byte offset in 64B fp8 row == channel offset
    int node = (blockIdx.x * 4 + w) * 16 + sub;
    int2 rb = rowbounds[node];
    float dn = dinv[node];
    uint4 su = *(const uint4*)(h + node * HID + qoff);  // hoisted (hB' has dinv_s)
    int gid = batch[node];                               // hoisted
    float r[16];
    agg_body16(rb.x, rb.y, csr, h, qoff, r);
    f32x2 s[8];
    s[0] = __builtin_amdgcn_cvt_pk_f32_fp8((int)su.x, false);
    s[1] = __builtin_amdgcn_cvt_pk_f32_fp8((int)su.x, true);
    s[2] = __builtin_amdgcn_cvt_pk_f32_fp8((int)su.y, false);
    s[3] = __builtin_amdgcn_cvt_pk_f32_fp8((int)su.y, true);
    s[4] = __builtin_amdgcn_cvt_pk_f32_fp8((int)su.z, false);
    s[5] = __builtin_amdgcn_cvt_pk_f32_fp8((int)su.z, true);
    s[6] = __builtin_amdgcn_cvt_pk_f32_fp8((int)su.w, false);
    s[7] = __builtin_amdgcn_cvt_pk_f32_fp8((int)su.w, true);
    int nl = w * 16 + sub;
    float* rp = &red[nl][qoff];
#pragma unroll
    for (int k = 0; k < 4; k++) {
        float4 bv = *(const float4*)&b[qoff + 4 * k];
        rp[4 * k + 0] = fmaxf(dn * (r[4 * k + 0] + s[2 * k][0]) + bv.x, 0.0f);
        rp[4 * k + 1] = fmaxf(dn * (r[4 * k + 1] + s[2 * k][1]) + bv.y, 0.0f);
        rp[4 * k + 2] = fmaxf(dn * (r[4 * k + 2] + s[2 * k + 1][0]) + bv.z, 0.0f);
        rp[4 * k + 3] = fmaxf(dn * (r[4 * k + 3] + s[2 * k + 1][1]) + bv.w, 0.0f);
    }
    if (q == 0) gids[nl] = gid;
    __syncthreads();
    if (tid < 64) {  // wave 0: run-length reduce 64 nodes (batch sorted)
        int c = tid;
        float acc = 0.0f;
        int cur = gids[0], cnt = 0;
        for (int n = 0; n < 64; n++) {
            int g = gids[n];
            if (g != cur) {
                atomicAdd(&pool[cur * HID + c], acc);
                if (c == 0) atomicAdd(&gcnt[cur], (float)cnt);
                acc = 0.0f; cnt = 0; cur = g;
            }
            acc += red[n][c];
            cnt++;
        }
        atomicAdd(&pool[cur * HID + c], acc);
        if (c == 0) atomicAdd(&gcnt[cur], (float)cnt);
    }
}

// ---- final: out = sigmoid((pool/cnt) @ Wfc + bfc) ----
__global__ void final_kernel(const float* __restrict__ pool, const float* __restrict__ gcnt,
                             const float* __restrict__ Wfc, const float* __restrict__ bfc,
                             float* __restrict__ out) {
    int idx = blockIdx.x * 256 + threadIdx.x;
    if (idx >= N_GRAPHS * OUT_CH) return;
    int g = idx >> 2, o = idx & 3;
    float inv = 1.0f / fmaxf(gcnt[g], 1.0f);
    float acc = bfc[o];
#pragma unroll
    for (int k = 0; k < HID; k++) acc += pool[g * HID + k] * inv * Wfc[k * OUT_CH + o];
    out[idx] = 1.0f / (1.0f + expf(-acc));
}

extern "C" void kernel_launch(void* const* d_in, const int* in_sizes, int n_in,
                              void* d_out, int out_size, void* d_ws, size_t ws_size,
                              hipStream_t stream) {
    const float* x   = (const float*)d_in[0];
    const int* eidx  = (const int*)d_in[1];
    const int* batch = (const int*)d_in[2];
    const float* W1  = (const float*)d_in[3];
    const float* b1  = (const float*)d_in[4];
    const float* W2  = (const float*)d_in[5];
    const float* b2  = (const float*)d_in[6];
    const float* Wfc = (const float*)d_in[7];
    const float* bfc = (const float*)d_in[8];
    float* out = (float*)d_out;

    const int* src = eidx;
    const int* dst = eidx + N_EDGES;

    // workspace layout (~33 MB)
    unsigned char* hB = (unsigned char*)d_ws;                 // 8.4 MB fp8 (+1 zero row)
    int*   csr    = (int*)(hB + (size_t)(N_NODES + 1) * HID); // 10.5 MB src<<6
    int*   staged = csr + (size_t)NBUCK * CSR_STRIDE;         // 9.4 MB bucket-strided
    float* dinv   = (float*)(staged + (size_t)NBUCK * STRIDE); // 512 KB
    int2*  rowbounds = (int2*)(dinv + N_NODES);               // 1 MB
    int*   bucket_count = (int*)(rowbounds + N_NODES);        // 2 KB
    float* pool   = (float*)(bucket_count + NBUCK);           // 512 KB
    float* gcnt   = pool + N_GRAPHS * HID;                    // 8 KB
    unsigned short* xb = (unsigned short*)(gcnt + N_GRAPHS);  // 3.1 MB bf16 [N+1,12]

    // single memset: bucket_count | pool | gcnt are contiguous
    hipMemsetAsync(bucket_count, 0,
                   (size_t)(NBUCK + N_GRAPHS * HID + N_GRAPHS) * 4, stream);

    // CSR build: bucket sort -> fused count/scan/place (+prescaled xcast)
    bucket_kernel<<<N_EDGES / CHUNK, 1024, 0, stream>>>(src, dst, bucket_count, staged);
    build_kernel<<<NBUCK, 256, 0, stream>>>(bucket_count, staged, rowbounds, dinv, csr, x, xb);

    // layer 1: fused gather + register-tiled W1+W2 (h1 LDS-only) -> fp8 hB'
    w1w2_kernel<<<N_NODES / 64, 256, 0, stream>>>(rowbounds, csr, dinv, xb, W1, b1, W2,
                                                  (unsigned int*)hB);

    // layer 2: gather + pool
    agg_pool_kernel<<<N_NODES / 64, 256, 0, stream>>>(rowbounds, csr, dinv, hB, b2, batch,
                                                      pool, gcnt);

    // head
    final_kernel<<<(N_GRAPHS * OUT_CH + 255) / 256, 256, 0, stream>>>(pool, gcnt, Wfc, bfc, out);
}

// Round 5
// 178.176 us; speedup vs baseline: 1.0230x; 1.0230x over previous
//
#include <hip/hip_runtime.h>
#include <hip/hip_bf16.h>

// GCN. CSR via 2-pass LDS bucket sort (R1: global-atomic count = 86us; LDS build ~15us).
// R2: agg_x fused into w1w2. R3: sW2->global, 6 blocks/CU: 180.8us. R4: 24B xb rows
// straddle lines (25% of edges pull 2 lines) -> flat; reverted.
// R5: gathers are L2-miss-byte bound (table x 8 XCD compulsory replication at ~0.9TB/s
// random-line service). xb -> fp8 e4m3 16B-aligned rows: table 4->2MB (w1w2 FETCH
// 38->~22MB), no straddle, L2-resident. Same error class as the fp8 hB table.
// Layer 2: single 8 MB fp8 table (R17: splitting doubles per-edge line requests).

#define N_NODES 131072
#define N_EDGES 2097152
#define N_GRAPHS 2048
#define IN_CH 12
#define HID 64
#define OUT_CH 4
#define NBUCK 512          // buckets of 256 dst nodes
#define CHUNK 8192         // edges per bucket_kernel block
#define STRIDE 4608        // staging capacity per bucket (mean 4096, sd 64)
#define CSR_STRIDE 5120    // csr capacity per bucket (padded mean ~4500)
#define CAP 5120           // build_kernel LDS image capacity (20.5 KB, int)

typedef float f32x2 __attribute__((ext_vector_type(2)));

// ---- pass A: LDS bucket sort of edges by dst>>8 into strided staging ----
__global__ __launch_bounds__(1024, 4)
void bucket_kernel(const int* __restrict__ src, const int* __restrict__ dst,
                   int* __restrict__ bucket_count, int* __restrict__ staged) {
    __shared__ int hist[NBUCK];
    __shared__ int lscan[NBUCK];
    __shared__ int gbase[NBUCK];
    __shared__ int cursor[NBUCK];
    __shared__ int sorted[CHUNK];  // 32 KB
    int tid = threadIdx.x;
    int base = blockIdx.x * CHUNK;
    if (tid < NBUCK) { hist[tid] = 0; cursor[tid] = 0; }
    __syncthreads();
    int d8[8], s8[8];
#pragma unroll
    for (int k = 0; k < 8; k++) {
        int i = base + k * 1024 + tid;
        d8[k] = dst[i];
        s8[k] = src[i];
        atomicAdd(&hist[d8[k] >> 8], 1);
    }
    __syncthreads();
    if (tid < NBUCK) lscan[tid] = hist[tid];
    __syncthreads();
    for (int off = 1; off < NBUCK; off <<= 1) {
        int u = (tid < NBUCK && tid >= off) ? lscan[tid - off] : 0;
        __syncthreads();
        if (tid < NBUCK) lscan[tid] += u;
        __syncthreads();
    }
    if (tid < NBUCK) gbase[tid] = atomicAdd(&bucket_count[tid], hist[tid]);
    __syncthreads();
#pragma unroll
    for (int k = 0; k < 8; k++) {
        int b = d8[k] >> 8;
        int start = lscan[b] - hist[b];
        int p = start + atomicAdd(&cursor[b], 1);
        sorted[p] = ((d8[k] & 255) << 17) | s8[k];
    }
    __syncthreads();
    int wid = tid >> 6, lane = tid & 63;
    int g16 = lane >> 4, k16 = lane & 15;
    for (int b0 = wid * 4; b0 < NBUCK; b0 += 64) {
        int b = b0 + g16;
        int cb = hist[b];
        int lbase = lscan[b] - cb;
        int gb = b * STRIDE + gbase[b];
        for (int k = k16; k < cb; k += 16) staged[gb + k] = sorted[lbase + k];
    }
}

// ---- per-bucket: count + scan + place in one kernel; + prescaled fp8 x cast ----
__global__ void build_kernel(const int* __restrict__ bucket_count, const int* __restrict__ staged,
                             int2* __restrict__ rowbounds, float* __restrict__ dinv,
                             int* __restrict__ csr, const float* __restrict__ x,
                             uint4* __restrict__ xb) {
    __shared__ int sl[STRIDE];     // 18.4 KB bucket slice
    __shared__ int image[CAP];     // 20.5 KB csr image (src<<6)
    __shared__ int cnt[256];
    __shared__ int scn[256];
    __shared__ int loff[256];
    __shared__ int cursor[256];
    __shared__ int totalS;
    int b = blockIdx.x;
    int tid = threadIdx.x;
    int count = bucket_count[b];
    const int* st = staged + b * STRIDE;
    cnt[tid] = 0;
    cursor[tid] = 0;
    for (int i = tid; i < count; i += 256) sl[i] = st[i];
    __syncthreads();
    for (int i = tid; i < count; i += 256) atomicAdd(&cnt[(sl[i] >> 17) & 255], 1);
    __syncthreads();
    int deg = cnt[tid];
    int degp = (deg + 3) & ~3;  // pad to x4
    scn[tid] = degp;
    __syncthreads();
    for (int off = 1; off < 256; off <<= 1) {
        int u = (tid >= off) ? scn[tid - off] : 0;
        __syncthreads();
        scn[tid] += u;
        __syncthreads();
    }
    int lo = scn[tid] - degp;
    loff[tid] = lo;
    int nbase = (b << 8) + tid;
    int gb = b * CSR_STRIDE;
    rowbounds[nbase] = make_int2(gb + lo, gb + lo + degp);
    float dv = rsqrtf((float)deg + 1.0f);
    dinv[nbase] = dv;
    if (tid == 255) totalS = lo + degp;
    {   // prescaled fp8 x cast: 12 ch -> 3 words + pad = 16B aligned row (2 MB table)
        const float* xp = x + nbase * IN_CH;
        unsigned o0 = (unsigned)__builtin_amdgcn_cvt_pk_fp8_f32(dv * xp[0], dv * xp[1], 0, false);
        o0 = (unsigned)__builtin_amdgcn_cvt_pk_fp8_f32(dv * xp[2], dv * xp[3], (int)o0, true);
        unsigned o1 = (unsigned)__builtin_amdgcn_cvt_pk_fp8_f32(dv * xp[4], dv * xp[5], 0, false);
        o1 = (unsigned)__builtin_amdgcn_cvt_pk_fp8_f32(dv * xp[6], dv * xp[7], (int)o1, true);
        unsigned o2 = (unsigned)__builtin_amdgcn_cvt_pk_fp8_f32(dv * xp[8], dv * xp[9], 0, false);
        o2 = (unsigned)__builtin_amdgcn_cvt_pk_fp8_f32(dv * xp[10], dv * xp[11], (int)o2, true);
        xb[nbase] = make_uint4(o0, o1, o2, 0);
    }
    if (b == 0 && tid == 0)  // zero row N_NODES of xb (pad target)
        xb[N_NODES] = make_uint4(0, 0, 0, 0);
    __syncthreads();
    for (int i = tid; i < count; i += 256) {
        int rec = sl[i];
        int s = rec & 0x1FFFF;
        int dq = (rec >> 17) & 255;
        int p = loff[dq] + atomicAdd(&cursor[dq], 1);
        int val = s << 6;  // byte off into 64B fp8 row | >>2: byte off into 16B xb row
        if (p < CAP) image[p] = val;
        else csr[gb + p] = val;
    }
    __syncthreads();
    int padval = N_NODES << 6;  // zero row
    for (int p = loff[tid] + deg; p < loff[tid] + degp; p++) {
        if (p < CAP) image[p] = padval;
        else csr[gb + p] = padval;
    }
    __syncthreads();
    int lim = totalS < CAP ? totalS : CAP;
    int* dstp = csr + gb;
    for (int i = tid; i < lim; i += 256) dstp[i] = image[i];
}

// ---- fp8 pair-unpack accumulate: uint2 = 8 ch ----
__device__ __forceinline__ void accq2(f32x2* a, uint2 u) {
    a[0] += __builtin_amdgcn_cvt_pk_f32_fp8((int)u.x, false);
    a[1] += __builtin_amdgcn_cvt_pk_f32_fp8((int)u.x, true);
    a[2] += __builtin_amdgcn_cvt_pk_f32_fp8((int)u.y, false);
    a[3] += __builtin_amdgcn_cvt_pk_f32_fp8((int)u.y, true);
}

// ---- fused layer-1 gather + w1 + w2, register-tiled: 64 nodes/block ----
// R5: xb fp8 16B rows; 4 thr/node = 2 edge-halves x 2 ch-halves (8B uint2 each);
// 8 edges in flight. LDS ~20KB, 6 blocks/CU.
__global__ __launch_bounds__(256, 6)
void w1w2_kernel(const int2* __restrict__ rowbounds, const int* __restrict__ csr,
                 const float* __restrict__ dinv, const unsigned char* __restrict__ xb,
                 const float* __restrict__ W1, const float* __restrict__ b1,
                 const float* __restrict__ W2, unsigned int* __restrict__ hout) {
    __shared__ float sA[64 * 13];          // 3.3 KB (pitch 13: 12 ch + 1 pad)
    __shared__ float sh1t[HID * 65];       // 16.25 KB: h1^T [ch][node], pitch 65
    int tid = threadIdx.x;
    int node0 = blockIdx.x * 64;
    {   // gather phase
        int nl = tid >> 2;
        int node = node0 + nl;
        int p = tid & 1, boff = 8 * p;  // bytes: p0 ch0-7, p1 ch8-15(pad)
        int2 rb = rowbounds[node];
        float dn = dinv[node];          // hoisted: issue early
        uint2 su = {0, 0};
        if (!(tid & 2)) su = *(const uint2*)(xb + node * 16 + boff);  // hoisted
        int len = rb.y - rb.x;
        int hlen = (len >> 3) << 2;     // first half, mult of 4
        int beg = (tid & 2) ? rb.x + hlen : rb.x;
        int end = (tid & 2) ? rb.y : rb.x + hlen;
        f32x2 a0[4] = {{0, 0}, {0, 0}, {0, 0}, {0, 0}};
        f32x2 a1[4] = {{0, 0}, {0, 0}, {0, 0}, {0, 0}};
        int j = beg;
        for (; j + 8 <= end; j += 8) {  // 8 edges in flight (uint2 loads are light)
            int4 ea = *(const int4*)(csr + j);
            int4 eb = *(const int4*)(csr + j + 4);
            uint2 u0 = *(const uint2*)(xb + (ea.x >> 2) + boff);
            uint2 u1 = *(const uint2*)(xb + (ea.y >> 2) + boff);
            uint2 u2 = *(const uint2*)(xb + (ea.z >> 2) + boff);
            uint2 u3 = *(const uint2*)(xb + (ea.w >> 2) + boff);
            uint2 u4 = *(const uint2*)(xb + (eb.x >> 2) + boff);
            uint2 u5 = *(const uint2*)(xb + (eb.y >> 2) + boff);
            uint2 u6 = *(const uint2*)(xb + (eb.z >> 2) + boff);
            uint2 u7 = *(const uint2*)(xb + (eb.w >> 2) + boff);
            accq2(a0, u0); accq2(a1, u1); accq2(a0, u2); accq2(a1, u3);
            accq2(a0, u4); accq2(a1, u5); accq2(a0, u6); accq2(a1, u7);
        }
        if (j < end) {  // exactly 4 padded edges remain
            int4 ea = *(const int4*)(csr + j);
            uint2 u0 = *(const uint2*)(xb + (ea.x >> 2) + boff);
            uint2 u1 = *(const uint2*)(xb + (ea.y >> 2) + boff);
            uint2 u2 = *(const uint2*)(xb + (ea.z >> 2) + boff);
            uint2 u3 = *(const uint2*)(xb + (ea.w >> 2) + boff);
            accq2(a0, u0); accq2(a1, u1); accq2(a0, u2); accq2(a1, u3);
        }
        f32x2 s0 = a0[0] + a1[0];
        f32x2 s1 = a0[1] + a1[1];
        f32x2 s2 = a0[2] + a1[2];
        f32x2 s3 = a0[3] + a1[3];
        s0[0] += __shfl_xor(s0[0], 2); s0[1] += __shfl_xor(s0[1], 2);
        s1[0] += __shfl_xor(s1[0], 2); s1[1] += __shfl_xor(s1[1], 2);
        s2[0] += __shfl_xor(s2[0], 2); s2[1] += __shfl_xor(s2[1], 2);
        s3[0] += __shfl_xor(s3[0], 2); s3[1] += __shfl_xor(s3[1], 2);
        if (!(tid & 2)) {
            s0 += __builtin_amdgcn_cvt_pk_f32_fp8((int)su.x, false);
            s1 += __builtin_amdgcn_cvt_pk_f32_fp8((int)su.x, true);
            s2 += __builtin_amdgcn_cvt_pk_f32_fp8((int)su.y, false);
            s3 += __builtin_amdgcn_cvt_pk_f32_fp8((int)su.y, true);
            // p=0 writes ch0-7; p=1 writes ch8-11 (s2,s3 are pad: not stored)
            float* dp = &sA[nl * 13 + 8 * p];
            dp[0] = dn * s0[0]; dp[1] = dn * s0[1];
            dp[2] = dn * s1[0]; dp[3] = dn * s1[1];
            if (p == 0) {
                dp[4] = dn * s2[0]; dp[5] = dn * s2[1];
                dp[6] = dn * s3[0]; dp[7] = dn * s3[1];
            }
        }
    }
    __syncthreads();
    // phase 1 (W1): wave w computes 16-node x 64-ch tile; lane = channel.
    // W1 column hoisted to 12 registers (global/L1, coalesced 256B per load).
    int w = tid >> 6, c = tid & 63;
    float bc = b1[c];
    float wk[IN_CH];
#pragma unroll
    for (int k = 0; k < IN_CH; k++) wk[k] = W1[k * HID + c];
#pragma unroll
    for (int it = 0; it < 4; it++) {
        int n0 = w * 16 + it * 4;
        float a0 = bc, a1 = bc, a2 = bc, a3 = bc;
#pragma unroll
        for (int k = 0; k < IN_CH; k++) {
            float wv = wk[k];
            a0 += sA[(n0 + 0) * 13 + k] * wv;  // sA reads broadcast per wave
            a1 += sA[(n0 + 1) * 13 + k] * wv;
            a2 += sA[(n0 + 2) * 13 + k] * wv;
            a3 += sA[(n0 + 3) * 13 + k] * wv;
        }
        float4 o = make_float4(fmaxf(a0, 0.0f), fmaxf(a1, 0.0f),
                               fmaxf(a2, 0.0f), fmaxf(a3, 0.0f));
        *(float4*)&sh1t[c * 65 + n0] = o;  // transposed: [ch][node]
    }
    __syncthreads();
    // phase 2 (W2): thread = 4 nodes x 4 ch; W2 from global (L1-resident 16KB)
    int nq = tid >> 4, c4 = (tid & 15) * 4;
    float4 a0 = {0, 0, 0, 0}, a1 = {0, 0, 0, 0}, a2 = {0, 0, 0, 0}, a3 = {0, 0, 0, 0};
#pragma unroll 4
    for (int k = 0; k < HID; k++) {
        float4 wv = *(const float4*)&W2[k * HID + c4];
        float4 hv = *(const float4*)&sh1t[k * 65 + nq * 4];  // 4 nodes' h1[k]
        a0.x += hv.x * wv.x; a0.y += hv.x * wv.y; a0.z += hv.x * wv.z; a0.w += hv.x * wv.w;
        a1.x += hv.y * wv.x; a1.y += hv.y * wv.y; a1.z += hv.y * wv.z; a1.w += hv.y * wv.w;
        a2.x += hv.z * wv.x; a2.y += hv.z * wv.y; a2.z += hv.z * wv.z; a2.w += hv.z * wv.w;
        a3.x += hv.w * wv.x; a3.y += hv.w * wv.y; a3.z += hv.w * wv.z; a3.w += hv.w * wv.w;
    }
    int nb = node0 + nq * 4;
    float dv0 = dinv[nb + 0], dv1 = dinv[nb + 1], dv2 = dinv[nb + 2], dv3 = dinv[nb + 3];
    unsigned int p0 = (unsigned int)__builtin_amdgcn_cvt_pk_fp8_f32(dv0 * a0.x, dv0 * a0.y, 0, false);
    p0 = (unsigned int)__builtin_amdgcn_cvt_pk_fp8_f32(dv0 * a0.z, dv0 * a0.w, (int)p0, true);
    unsigned int p1 = (unsigned int)__builtin_amdgcn_cvt_pk_fp8_f32(dv1 * a1.x, dv1 * a1.y, 0, false);
    p1 = (unsigned int)__builtin_amdgcn_cvt_pk_fp8_f32(dv1 * a1.z, dv1 * a1.w, (int)p1, true);
    unsigned int p2 = (unsigned int)__builtin_amdgcn_cvt_pk_fp8_f32(dv2 * a2.x, dv2 * a2.y, 0, false);
    p2 = (unsigned int)__builtin_amdgcn_cvt_pk_fp8_f32(dv2 * a2.z, dv2 * a2.w, (int)p2, true);
    unsigned int p3 = (unsigned int)__builtin_amdgcn_cvt_pk_fp8_f32(dv3 * a3.x, dv3 * a3.y, 0, false);
    p3 = (unsigned int)__builtin_amdgcn_cvt_pk_fp8_f32(dv3 * a3.z, dv3 * a3.w, (int)p3, true);
    int cl = c4 >> 2;
    hout[(nb + 0) * 16 + cl] = p0;   // per-instruction: 64B runs, fully coalesced
    hout[(nb + 1) * 16 + cl] = p1;
    hout[(nb + 2) * 16 + cl] = p2;
    hout[(nb + 3) * 16 + cl] = p3;
    if (blockIdx.x == 0 && tid < 16)  // zero row N_NODES (pad target)
        hout[(size_t)N_NODES * 16 + tid] = 0;
}

// ---- layer-2 fp8 gather body: 4 thr/node, uint4 (16 ch); 8 edges in flight ----
__device__ __forceinline__ void add_fp8q(f32x2* a, uint4 u) {
    a[0] += __builtin_amdgcn_cvt_pk_f32_fp8((int)u.x, false);
    a[1] += __builtin_amdgcn_cvt_pk_f32_fp8((int)u.x, true);
    a[2] += __builtin_amdgcn_cvt_pk_f32_fp8((int)u.y, false);
    a[3] += __builtin_amdgcn_cvt_pk_f32_fp8((int)u.y, true);
    a[4] += __builtin_amdgcn_cvt_pk_f32_fp8((int)u.z, false);
    a[5] += __builtin_amdgcn_cvt_pk_f32_fp8((int)u.z, true);
    a[6] += __builtin_amdgcn_cvt_pk_f32_fp8((int)u.w, false);
    a[7] += __builtin_amdgcn_cvt_pk_f32_fp8((int)u.w, true);
}

__device__ __forceinline__ void agg_body16(int beg, int end, const int* __restrict__ csr,
                                           const unsigned char* __restrict__ h,
                                           int qoff, float* r) {
    f32x2 a0[8] = {{0, 0}, {0, 0}, {0, 0}, {0, 0}, {0, 0}, {0, 0}, {0, 0}, {0, 0}};
    f32x2 a1[8] = {{0, 0}, {0, 0}, {0, 0}, {0, 0}, {0, 0}, {0, 0}, {0, 0}, {0, 0}};
    int j = beg;
    for (; j + 8 <= end; j += 8) {  // 8 edges in flight
        int4 ea = *(const int4*)(csr + j);
        int4 eb = *(const int4*)(csr + j + 4);
        uint4 u0 = *(const uint4*)(h + ea.x + qoff);
        uint4 u1 = *(const uint4*)(h + ea.y + qoff);
        uint4 u2 = *(const uint4*)(h + ea.z + qoff);
        uint4 u3 = *(const uint4*)(h + ea.w + qoff);
        uint4 u4 = *(const uint4*)(h + eb.x + qoff);
        uint4 u5 = *(const uint4*)(h + eb.y + qoff);
        uint4 u6 = *(const uint4*)(h + eb.z + qoff);
        uint4 u7 = *(const uint4*)(h + eb.w + qoff);
        add_fp8q(a0, u0); add_fp8q(a1, u1); add_fp8q(a0, u2); add_fp8q(a1, u3);
        add_fp8q(a0, u4); add_fp8q(a1, u5); add_fp8q(a0, u6); add_fp8q(a1, u7);
    }
    if (j < end) {  // exactly 4 padded edges remain
        int4 ea = *(const int4*)(csr + j);
        uint4 u0 = *(const uint4*)(h + ea.x + qoff);
        uint4 u1 = *(const uint4*)(h + ea.y + qoff);
        uint4 u2 = *(const uint4*)(h + ea.z + qoff);
        uint4 u3 = *(const uint4*)(h + ea.w + qoff);
        add_fp8q(a0, u0); add_fp8q(a1, u1); add_fp8q(a0, u2); add_fp8q(a1, u3);
    }
#pragma unroll
    for (int k = 0; k < 8; k++) {
        f32x2 s = a0[k] + a1[k];
        r[2 * k] = s[0];
        r[2 * k + 1] = s[1];
    }
}

// ---- layer-2 gather-aggregate + relu + fused mean-pool (run-length flush) ----
__global__ void agg_pool_kernel(const int2* __restrict__ rowbounds, const int* __restrict__ csr,
                                const float* __restrict__ dinv,
                                const unsigned char* __restrict__ h,
                                const float* __restrict__ b, const int* __restrict__ batch,
                                float* __restrict__ pool, float* __restrict__ gcnt) {
    __shared__ float red[64][HID + 4];  // 17 KB, padded pitch kills bank conflicts
    __shared__ int gids[64];
    int tid = threadIdx.x;
    int w = tid >> 6, lane = tid & 63, sub = lane >> 2, q = lane & 3;
    int qoff = 16 * q;  // byte offset in 64B fp8 row == channel offset
    int node = (blockIdx.x * 4 + w) * 16 + sub;
    int2 rb = rowbounds[node];
    float dn = dinv[node];
    uint4 su = *(const uint4*)(h + node * HID + qoff);  // hoisted (hB' has dinv_s)
    int gid = batch[node];                               // hoisted
    float r[16];
    agg_body16(rb.x, rb.y, csr, h, qoff, r);
    f32x2 s[8];
    s[0] = __builtin_amdgcn_cvt_pk_f32_fp8((int)su.x, false);
    s[1] = __builtin_amdgcn_cvt_pk_f32_fp8((int)su.x, true);
    s[2] = __builtin_amdgcn_cvt_pk_f32_fp8((int)su.y, false);
    s[3] = __builtin_amdgcn_cvt_pk_f32_fp8((int)su.y, true);
    s[4] = __builtin_amdgcn_cvt_pk_f32_fp8((int)su.z, false);
    s[5] = __builtin_amdgcn_cvt_pk_f32_fp8((int)su.z, true);
    s[6] = __builtin_amdgcn_cvt_pk_f32_fp8((int)su.w, false);
    s[7] = __builtin_amdgcn_cvt_pk_f32_fp8((int)su.w, true);
    int nl = w * 16 + sub;
    float* rp = &red[nl][qoff];
#pragma unroll
    for (int k = 0; k < 4; k++) {
        float4 bv = *(const float4*)&b[qoff + 4 * k];
        rp[4 * k + 0] = fmaxf(dn * (r[4 * k + 0] + s[2 * k][0]) + bv.x, 0.0f);
        rp[4 * k + 1] = fmaxf(dn * (r[4 * k + 1] + s[2 * k][1]) + bv.y, 0.0f);
        rp[4 * k + 2] = fmaxf(dn * (r[4 * k + 2] + s[2 * k + 1][0]) + bv.z, 0.0f);
        rp[4 * k + 3] = fmaxf(dn * (r[4 * k + 3] + s[2 * k + 1][1]) + bv.w, 0.0f);
    }
    if (q == 0) gids[nl] = gid;
    __syncthreads();
    if (tid < 64) {  // wave 0: run-length reduce 64 nodes (batch sorted)
        int c = tid;
        float acc = 0.0f;
        int cur = gids[0], cnt = 0;
        for (int n = 0; n < 64; n++) {
            int g = gids[n];
            if (g != cur) {
                atomicAdd(&pool[cur * HID + c], acc);
                if (c == 0) atomicAdd(&gcnt[cur], (float)cnt);
                acc = 0.0f; cnt = 0; cur = g;
            }
            acc += red[n][c];
            cnt++;
        }
        atomicAdd(&pool[cur * HID + c], acc);
        if (c == 0) atomicAdd(&gcnt[cur], (float)cnt);
    }
}

// ---- final: out = sigmoid((pool/cnt) @ Wfc + bfc) ----
__global__ void final_kernel(const float* __restrict__ pool, const float* __restrict__ gcnt,
                             const float* __restrict__ Wfc, const float* __restrict__ bfc,
                             float* __restrict__ out) {
    int idx = blockIdx.x * 256 + threadIdx.x;
    if (idx >= N_GRAPHS * OUT_CH) return;
    int g = idx >> 2, o = idx & 3;
    float inv = 1.0f / fmaxf(gcnt[g], 1.0f);
    float acc = bfc[o];
#pragma unroll
    for (int k = 0; k < HID; k++) acc += pool[g * HID + k] * inv * Wfc[k * OUT_CH + o];
    out[idx] = 1.0f / (1.0f + expf(-acc));
}

extern "C" void kernel_launch(void* const* d_in, const int* in_sizes, int n_in,
                              void* d_out, int out_size, void* d_ws, size_t ws_size,
                              hipStream_t stream) {
    const float* x   = (const float*)d_in[0];
    const int* eidx  = (const int*)d_in[1];
    const int* batch = (const int*)d_in[2];
    const float* W1  = (const float*)d_in[3];
    const float* b1  = (const float*)d_in[4];
    const float* W2  = (const float*)d_in[5];
    const float* b2  = (const float*)d_in[6];
    const float* Wfc = (const float*)d_in[7];
    const float* bfc = (const float*)d_in[8];
    float* out = (float*)d_out;

    const int* src = eidx;
    const int* dst = eidx + N_EDGES;

    // workspace layout (~32 MB)
    unsigned char* hB = (unsigned char*)d_ws;                 // 8.4 MB fp8 (+1 zero row)
    int*   csr    = (int*)(hB + (size_t)(N_NODES + 1) * HID); // 10.5 MB src<<6
    int*   staged = csr + (size_t)NBUCK * CSR_STRIDE;         // 9.4 MB bucket-strided
    float* dinv   = (float*)(staged + (size_t)NBUCK * STRIDE); // 512 KB
    int2*  rowbounds = (int2*)(dinv + N_NODES);               // 1 MB
    int*   bucket_count = (int*)(rowbounds + N_NODES);        // 2 KB
    float* pool   = (float*)(bucket_count + NBUCK);           // 512 KB
    float* gcnt   = pool + N_GRAPHS * HID;                    // 8 KB
    uint4* xb     = (uint4*)(gcnt + N_GRAPHS);                // 2 MB fp8 [N+1,16B]

    // single memset: bucket_count | pool | gcnt are contiguous
    hipMemsetAsync(bucket_count, 0,
                   (size_t)(NBUCK + N_GRAPHS * HID + N_GRAPHS) * 4, stream);

    // CSR build: bucket sort -> fused count/scan/place (+prescaled fp8 xcast)
    bucket_kernel<<<N_EDGES / CHUNK, 1024, 0, stream>>>(src, dst, bucket_count, staged);
    build_kernel<<<NBUCK, 256, 0, stream>>>(bucket_count, staged, rowbounds, dinv, csr, x, xb);

    // layer 1: fused gather + register-tiled W1+W2 (h1 LDS-only) -> fp8 hB'
    w1w2_kernel<<<N_NODES / 64, 256, 0, stream>>>(rowbounds, csr, dinv,
                                                  (const unsigned char*)xb, W1, b1, W2,
                                                  (unsigned int*)hB);

    // layer 2: gather + pool
    agg_pool_kernel<<<N_NODES / 64, 256, 0, stream>>>(rowbounds, csr, dinv, hB, b2, batch,
                                                      pool, gcnt);

    // head
    final_kernel<<<(N_GRAPHS * OUT_CH + 255) / 256, 256, 0, stream>>>(pool, gcnt, Wfc, bfc, out);
}